// Round 5
// baseline (1807.647 us; speedup 1.0000x reference)
//
#include <hip/hip_runtime.h>

typedef __attribute__((ext_vector_type(8))) short short8;
typedef __attribute__((ext_vector_type(4))) float f32x4;

#define GLBP(p) ((const __attribute__((address_space(1))) void*)(p))
#define LDSP(p) ((__attribute__((address_space(3))) void*)(p))

__device__ __forceinline__ float bf2f(unsigned short u) {
  return __uint_as_float(((unsigned int)u) << 16);
}
__device__ __forceinline__ unsigned short f2bf(float f) {
  unsigned int u = __float_as_uint(f);
  u += 0x7fff + ((u >> 16) & 1);
  return (unsigned short)(u >> 16);
}

// global token -> (batch, pixel-y, pixel-x); windows are 14x14, 5x5 grid/batch
__device__ __forceinline__ void tok2pix(int gt, int& b, int& py, int& px) {
  int w = gt / 196, t = gt - w * 196;
  b = w / 25;
  int wr = w - b * 25;
  int wy = wr / 5, wx = wr - wy * 5;
  int ty = t / 14;
  py = wy * 14 + ty;
  px = wx * 14 + (t - ty * 14);
}

// ---------------- weight transpose fp32(K,N) -> bf16(N,K) ----------------
__global__ void k_transpose(const float* __restrict__ W, unsigned short* __restrict__ Wt,
                            int K, int N) {
  __shared__ float tile[32][33];
  int tx = threadIdx.x, ty = threadIdx.y;
  int n0 = blockIdx.x * 32, k0 = blockIdx.y * 32;
#pragma unroll
  for (int i = 0; i < 4; ++i)
    tile[ty + 8 * i][tx] = W[(size_t)(k0 + ty + 8 * i) * N + n0 + tx];
  __syncthreads();
#pragma unroll
  for (int i = 0; i < 4; ++i)
    Wt[(size_t)(n0 + ty + 8 * i) * K + k0 + tx] = f2bf(tile[tx][ty + 8 * i]);
}

// ---------------- LN1: one wave per token row ----------------
__global__ __launch_bounds__(256) void k_ln1(const float* __restrict__ x,
                                             const float* __restrict__ g,
                                             const float* __restrict__ be,
                                             unsigned short* __restrict__ A1,
                                             int w0, int ctok) {
  int m = blockIdx.x * 4 + (threadIdx.x >> 6);
  int lane = threadIdx.x & 63;
  int b, py, px;
  tok2pix(w0 * 196 + m, b, py, px);
  bool valid = (m < ctok) && (py < 64) && (px < 64);
  const float* row = x + ((size_t)((b * 64 + py) * 64 + px)) * 1280;
  float v[20];
#pragma unroll
  for (int i = 0; i < 20; ++i) v[i] = valid ? row[lane + 64 * i] : 0.f;
  float s = 0.f, ss = 0.f;
#pragma unroll
  for (int i = 0; i < 20; ++i) { s += v[i]; ss += v[i] * v[i]; }
#pragma unroll
  for (int o = 32; o > 0; o >>= 1) { s += __shfl_down(s, o); ss += __shfl_down(ss, o); }
  s = __shfl(s, 0);
  ss = __shfl(ss, 0);
  float mu = s * (1.f / 1280.f);
  float var = ss * (1.f / 1280.f) - mu * mu;
  float rinv = rsqrtf(var + 1e-6f);
  unsigned short* o1 = A1 + (size_t)m * 1280;
#pragma unroll
  for (int i = 0; i < 20; ++i) {
    int c = lane + 64 * i;
    o1[c] = f2bf((v[i] - mu) * rinv * g[c] + be[c]);
  }
}

// ---------------- LN2: one wave per bf16 row ----------------
__global__ __launch_bounds__(256) void k_ln2(const unsigned short* __restrict__ AT,
                                             const float* __restrict__ g,
                                             const float* __restrict__ be,
                                             unsigned short* __restrict__ A2) {
  int m = blockIdx.x * 4 + (threadIdx.x >> 6);
  int lane = threadIdx.x & 63;
  const unsigned short* row = AT + (size_t)m * 1280;
  float v[20];
#pragma unroll
  for (int i = 0; i < 20; ++i) v[i] = bf2f(row[lane + 64 * i]);
  float s = 0.f, ss = 0.f;
#pragma unroll
  for (int i = 0; i < 20; ++i) { s += v[i]; ss += v[i] * v[i]; }
#pragma unroll
  for (int o = 32; o > 0; o >>= 1) { s += __shfl_down(s, o); ss += __shfl_down(ss, o); }
  s = __shfl(s, 0);
  ss = __shfl(ss, 0);
  float mu = s * (1.f / 1280.f);
  float var = ss * (1.f / 1280.f) - mu * mu;
  float rinv = rsqrtf(var + 1e-6f);
  unsigned short* o1 = A2 + (size_t)m * 1280;
#pragma unroll
  for (int i = 0; i < 20; ++i) {
    int c = lane + 64 * i;
    o1[c] = f2bf((v[i] - mu) * rinv * g[c] + be[c]);
  }
}

// ---------------- 256x128 bf16 GEMM, BK=64, 3-slot ring, counted vmcnt(6) ----------------
// C[M,N] = A[M,K] * Bt[N,K]^T ; one barrier + one vmcnt per K-tile, never drains mid-loop.
// Swizzle: byte ^= ((row&7)<<4) within each 128B LDS row (applied to stage source AND reads).
// EPI 0: +bias->bf16 (QKV)  1: +bias+win-residual->bf16 (proj)
//     2: +bias+gelu->bf16 (MLP1)  3: +bias+attnres->f32 out, crop (MLP2)
template <int EPI>
__device__ __forceinline__ void gemm_body(const unsigned short* __restrict__ A,
                                          const unsigned short* __restrict__ Bt,
                                          int K, int N, int gx,
                                          const float* __restrict__ bias,
                                          void* __restrict__ outp,
                                          const float* __restrict__ xres,
                                          const unsigned short* __restrict__ attnres,
                                          int w0, int ctok) {
  __shared__ __align__(16) char smem[147456];  // 3 slots x (A 32KB + B 16KB)
  int tid = threadIdx.x;
  int w = tid >> 6, lane = tid & 63;
  // bijective XCD swizzle (m204)
  int nwg = gridDim.x, bid = blockIdx.x;
  int q = nwg >> 3, r = nwg & 7;
  int xcd = bid & 7, loc = bid >> 3;
  int wg = (xcd < r ? xcd * (q + 1) : r * (q + 1) + (xcd - r) * q) + loc;
  int bx = wg % gx, by = wg / gx;
  int mBase = by * 256, nBase = bx * 128;
  int wr = w >> 2, wc = w & 3;
  int la = lane & 15, lg = lane >> 4;

  // staging: thread covers LDS bytes (i*8192 + tid*16) of each region
  int srow = tid >> 3;                                  // 0..63
  int ssw = ((tid & 7) * 16) ^ ((srow & 7) << 4);       // pre-swizzled in-row byte
  const char* pa[4];
  const char* pb[2];
#pragma unroll
  for (int i = 0; i < 4; ++i)
    pa[i] = (const char*)A + ((size_t)(mBase + srow + i * 64) * K) * 2 + ssw;
#pragma unroll
  for (int i = 0; i < 2; ++i)
    pb[i] = (const char*)Bt + ((size_t)(nBase + srow + i * 64) * K) * 2 + ssw;
  int ldst = tid * 16;

  auto STAGE = [&](int sb, size_t ko) {
#pragma unroll
    for (int i = 0; i < 4; ++i)
      __builtin_amdgcn_global_load_lds(GLBP(pa[i] + ko), LDSP(smem + sb + i * 8192 + ldst), 16, 0, 0);
#pragma unroll
    for (int i = 0; i < 2; ++i)
      __builtin_amdgcn_global_load_lds(GLBP(pb[i] + ko), LDSP(smem + sb + 32768 + i * 8192 + ldst), 16, 0, 0);
  };

  // read offsets (per-thread constants)
  int colk[2];
#pragma unroll
  for (int kk = 0; kk < 2; ++kk) colk[kk] = (kk * 64 + lg * 16) ^ ((la & 7) << 4);
  int offA[8];
#pragma unroll
  for (int m = 0; m < 8; ++m) offA[m] = (wr * 128 + m * 16 + la) * 128;
  int offB[2];
#pragma unroll
  for (int n = 0; n < 2; ++n) offB[n] = 32768 + (wc * 32 + n * 16 + la) * 128;

  const f32x4 z4 = {0.f, 0.f, 0.f, 0.f};
  f32x4 acc[8][2];
#pragma unroll
  for (int m = 0; m < 8; ++m)
#pragma unroll
    for (int n = 0; n < 2; ++n) acc[m][n] = z4;

  int NT = K >> 6;
  STAGE(0, 0);
  STAGE(49152, 128);
  int rs = 0;
  for (int t = 0; t < NT; ++t) {
    if (t + 1 < NT)
      asm volatile("s_waitcnt vmcnt(6)" ::: "memory");
    else
      asm volatile("s_waitcnt vmcnt(0)" ::: "memory");
    __builtin_amdgcn_s_barrier();
    __builtin_amdgcn_sched_barrier(0);
    const char* buf = (const char*)smem + rs * 49152;
    if (t + 2 < NT) {
      int ws = rs + 2;
      if (ws >= 3) ws -= 3;
      STAGE(ws * 49152, (size_t)(t + 2) * 128);
    }
    short8 bfr[2][2], af[4][2];
#pragma unroll
    for (int n = 0; n < 2; ++n)
#pragma unroll
      for (int kk = 0; kk < 2; ++kk) bfr[n][kk] = *(const short8*)(buf + offB[n] + colk[kk]);
#pragma unroll
    for (int m = 0; m < 4; ++m)
#pragma unroll
      for (int kk = 0; kk < 2; ++kk) af[m][kk] = *(const short8*)(buf + offA[m] + colk[kk]);
    __builtin_amdgcn_s_setprio(1);
#pragma unroll
    for (int m = 0; m < 4; ++m)
#pragma unroll
      for (int n = 0; n < 2; ++n)
#pragma unroll
        for (int kk = 0; kk < 2; ++kk)
          acc[m][n] = __builtin_amdgcn_mfma_f32_16x16x32_bf16(af[m][kk], bfr[n][kk], acc[m][n], 0, 0, 0);
    __builtin_amdgcn_s_setprio(0);
    __builtin_amdgcn_sched_barrier(0);
#pragma unroll
    for (int m = 0; m < 4; ++m)
#pragma unroll
      for (int kk = 0; kk < 2; ++kk) af[m][kk] = *(const short8*)(buf + offA[m + 4] + colk[kk]);
    __builtin_amdgcn_s_setprio(1);
#pragma unroll
    for (int m = 0; m < 4; ++m)
#pragma unroll
      for (int n = 0; n < 2; ++n)
#pragma unroll
        for (int kk = 0; kk < 2; ++kk)
          acc[m + 4][n] = __builtin_amdgcn_mfma_f32_16x16x32_bf16(af[m][kk], bfr[n][kk], acc[m + 4][n], 0, 0, 0);
    __builtin_amdgcn_s_setprio(0);
    rs = (rs == 2) ? 0 : rs + 1;
  }

#pragma unroll
  for (int m = 0; m < 8; ++m) {
#pragma unroll
    for (int n = 0; n < 2; ++n) {
      int col = nBase + wc * 32 + n * 16 + la;
      float bcol = bias[col];
#pragma unroll
      for (int j = 0; j < 4; ++j) {
        int row = mBase + wr * 128 + m * 16 + lg * 4 + j;
        float v = acc[m][n][j] + bcol;
        if (EPI == 0) {
          ((unsigned short*)outp)[(size_t)row * N + col] = f2bf(v);
        } else if (EPI == 2) {
          float gg = 0.5f * v * (1.f + erff(v * 0.70710678118654752f));
          ((unsigned short*)outp)[(size_t)row * N + col] = f2bf(gg);
        } else if (EPI == 1) {
          if (row < ctok) {
            int b, py, px;
            tok2pix(w0 * 196 + row, b, py, px);
            float wv = (py < 64 && px < 64)
                           ? xres[((size_t)((b * 64 + py) * 64 + px)) * 1280 + col]
                           : 0.f;
            ((unsigned short*)outp)[(size_t)row * 1280 + col] = f2bf(v + wv);
          }
        } else {
          if (row < ctok) {
            int b, py, px;
            tok2pix(w0 * 196 + row, b, py, px);
            if (py < 64 && px < 64)
              ((float*)outp)[((size_t)((b * 64 + py) * 64 + px)) * 1280 + col] =
                  v + bf2f(attnres[(size_t)row * 1280 + col]);
          }
        }
      }
    }
  }
}

__global__ __launch_bounds__(512, 2) void k_gqkv(const unsigned short* A, const unsigned short* Bt,
                                                 int K, int N, int gx, const float* bias, void* o,
                                                 const float* xr, const unsigned short* ar, int w0, int ct) {
  gemm_body<0>(A, Bt, K, N, gx, bias, o, xr, ar, w0, ct);
}
__global__ __launch_bounds__(512, 2) void k_gproj(const unsigned short* A, const unsigned short* Bt,
                                                  int K, int N, int gx, const float* bias, void* o,
                                                  const float* xr, const unsigned short* ar, int w0, int ct) {
  gemm_body<1>(A, Bt, K, N, gx, bias, o, xr, ar, w0, ct);
}
__global__ __launch_bounds__(512, 2) void k_gmlp1(const unsigned short* A, const unsigned short* Bt,
                                                  int K, int N, int gx, const float* bias, void* o,
                                                  const float* xr, const unsigned short* ar, int w0, int ct) {
  gemm_body<2>(A, Bt, K, N, gx, bias, o, xr, ar, w0, ct);
}
__global__ __launch_bounds__(512, 2) void k_gmlp2(const unsigned short* A, const unsigned short* Bt,
                                                  int K, int N, int gx, const float* bias, void* o,
                                                  const float* xr, const unsigned short* ar, int w0, int ct) {
  gemm_body<3>(A, Bt, K, N, gx, bias, o, xr, ar, w0, ct);
}

// ---------------- decomposed rel-pos bias (bf16): B[wh][t][0..13]=bias_h(ky), [14..27]=bias_w(kx) ----------------
__global__ __launch_bounds__(256) void k_relbias(const unsigned short* __restrict__ qkv,
                                                 const float* __restrict__ rph,
                                                 const float* __restrict__ rpw,
                                                 unsigned short* __restrict__ B) {
  int wh = blockIdx.x;
  int w = wh >> 4, nh = wh & 15;
  const unsigned short* qb = qkv + (size_t)w * 196 * 3840 + nh * 80;
  for (int id = threadIdx.x; id < 196 * 28; id += 256) {
    int t = id / 28, which = id - t * 28;
    int y = t / 14, xx = t - y * 14;
    const float* R = (which < 14) ? (rph + (size_t)(y - which + 13) * 80)
                                  : (rpw + (size_t)(xx - (which - 14) + 13) * 80);
    const unsigned short* qq = qb + (size_t)t * 3840;
    float acc = 0.f;
#pragma unroll
    for (int d8 = 0; d8 < 10; ++d8) {
      short8 qv = *(const short8*)(qq + d8 * 8);
      const float4* Rv = (const float4*)(R + d8 * 8);
      float4 ra = Rv[0], rb = Rv[1];
      acc += bf2f((unsigned short)qv[0]) * ra.x + bf2f((unsigned short)qv[1]) * ra.y +
             bf2f((unsigned short)qv[2]) * ra.z + bf2f((unsigned short)qv[3]) * ra.w +
             bf2f((unsigned short)qv[4]) * rb.x + bf2f((unsigned short)qv[5]) * rb.y +
             bf2f((unsigned short)qv[6]) * rb.z + bf2f((unsigned short)qv[7]) * rb.w;
    }
    B[(size_t)wh * (196 * 28) + id] = f2bf(acc);
  }
}

// ---------------- attention: one block (512 thr, 8 waves) per (window, head) ----------------
__global__ __launch_bounds__(512) void k_attn(const unsigned short* __restrict__ qkv,
                                              const unsigned short* __restrict__ Bias,
                                              unsigned short* __restrict__ AO) {
  __shared__ unsigned short Ks[208 * 104];  // [key][d] (stride 52dw: 2-way free)
  __shared__ unsigned short Vt[80 * 248];   // [d][key] (stride 124dw: 2-way free)
  __shared__ unsigned short Ps[8][16 * 248];
  __shared__ unsigned short Bls[196 * 28];  // bf16 bias rows
  int wh = blockIdx.x;
  int w = wh >> 4, nh = wh & 15;
  int tid = threadIdx.x, wid = tid >> 6, lane = tid & 63;
  int la = lane & 15, lg = lane >> 4;
  const unsigned short* base = qkv + (size_t)w * 196 * 3840 + nh * 80;
  const short8 z8 = {0, 0, 0, 0, 0, 0, 0, 0};

  // K: 208 rows x 13 segs of 8 (cols 80..103 and rows >=196 zeroed)
  for (int c = tid; c < 208 * 13; c += 512) {
    int t = c / 13, seg = c - t * 13;
    short8 kv = z8;
    if (t < 196 && seg < 10) kv = *(const short8*)(base + (size_t)t * 3840 + 1280 + seg * 8);
    *(short8*)(Ks + t * 104 + seg * 8) = kv;
  }
  // V: coalesced 16B row reads, scatter-transpose into Vt[d][t]
  for (int c = tid; c < 196 * 10; c += 512) {
    int t = c / 10, d8 = (c - t * 10) * 8;
    short8 vv = *(const short8*)(base + (size_t)t * 3840 + 2560 + d8);
#pragma unroll
    for (int e = 0; e < 8; ++e) Vt[(d8 + e) * 248 + t] = (unsigned short)vv[e];
  }
  for (int i = tid; i < 80 * 28; i += 512) Vt[(i / 28) * 248 + 196 + (i % 28)] = 0;
  // bias rows -> LDS
  for (int i = tid; i < 196 * 28; i += 512) Bls[i] = Bias[(size_t)wh * (196 * 28) + i];
  __syncthreads();

  int kyv[13], kxv[13];
#pragma unroll
  for (int ci = 0; ci < 13; ++ci) {
    int key = ci * 16 + la;
    kyv[ci] = key / 14;
    kxv[ci] = key - kyv[ci] * 14;
  }

  const float scale = 0.111803398874989485f;  // 80^-0.5
  const f32x4 z4 = {0.f, 0.f, 0.f, 0.f};
  unsigned short* P = Ps[wid];

  auto process = [&](int rb) {
    short8 qa[3];
#pragma unroll
    for (int kk = 0; kk < 3; ++kk) {
      int t = rb * 16 + la;
      int d = kk * 32 + lg * 8;
      qa[kk] = (t < 196 && d < 80) ? *(const short8*)(base + (size_t)t * 3840 + d) : z8;
    }
    f32x4 s[13];
#pragma unroll
    for (int i = 0; i < 13; ++i) s[i] = z4;
#pragma unroll
    for (int kk = 0; kk < 3; ++kk) {
#pragma unroll
      for (int ni = 0; ni < 13; ++ni) {
        short8 bb = *(const short8*)(Ks + (ni * 16 + la) * 104 + kk * 32 + lg * 8);
        s[ni] = __builtin_amdgcn_mfma_f32_16x16x32_bf16(qa[kk], bb, s[ni], 0, 0, 0);
      }
    }
#pragma unroll
    for (int j = 0; j < 4; ++j) {
      int rloc = lg * 4 + j;
      int t = rb * 16 + rloc;
      bool tval = t < 196;
      const unsigned short* Bp = Bls + (tval ? t : 0) * 28;
      float v[13];
      float mx = -3e30f;
#pragma unroll
      for (int ci = 0; ci < 13; ++ci) {
        int key = ci * 16 + la;
        float val = s[ci][j] * scale;
        if (key < 196 && tval) val += bf2f(Bp[kyv[ci]]) + bf2f(Bp[14 + kxv[ci]]);
        if (key >= 196) val = -3e30f;
        v[ci] = val;
        mx = fmaxf(mx, val);
      }
#pragma unroll
      for (int o = 1; o < 16; o <<= 1) mx = fmaxf(mx, __shfl_xor(mx, o));
      float sum = 0.f;
#pragma unroll
      for (int ci = 0; ci < 13; ++ci) {
        float e = __expf(v[ci] - mx);
        v[ci] = e;
        sum += e;
      }
#pragma unroll
      for (int o = 1; o < 16; o <<= 1) sum += __shfl_xor(sum, o);
      float inv = 1.f / sum;
#pragma unroll
      for (int ci = 0; ci < 13; ++ci) P[rloc * 248 + ci * 16 + la] = f2bf(v[ci] * inv);
      P[rloc * 248 + 208 + la] = 0;
    }
    f32x4 o5[5];
#pragma unroll
    for (int i = 0; i < 5; ++i) o5[i] = z4;
#pragma unroll
    for (int kc = 0; kc < 7; ++kc) {
      short8 a = *(const short8*)(P + la * 248 + kc * 32 + lg * 8);
#pragma unroll
      for (int ni = 0; ni < 5; ++ni) {
        short8 bb = *(const short8*)(Vt + (ni * 16 + la) * 248 + kc * 32 + lg * 8);
        o5[ni] = __builtin_amdgcn_mfma_f32_16x16x32_bf16(a, bb, o5[ni], 0, 0, 0);
      }
    }
#pragma unroll
    for (int ni = 0; ni < 5; ++ni)
#pragma unroll
      for (int j = 0; j < 4; ++j) {
        int t = rb * 16 + lg * 4 + j;
        if (t < 196)
          AO[((size_t)w * 196 + t) * 1280 + nh * 80 + ni * 16 + la] = f2bf(o5[ni][j]);
      }
  };

  process(wid);                   // rb 0..7
  if (wid < 5) process(wid + 8);  // rb 8..12
}

extern "C" void kernel_launch(void* const* d_in, const int* in_sizes, int n_in,
                              void* d_out, int out_size, void* d_ws, size_t ws_size,
                              hipStream_t stream) {
  const float* x = (const float*)d_in[0];
  const float* ln1g = (const float*)d_in[1];
  const float* ln1b = (const float*)d_in[2];
  const float* qkvw = (const float*)d_in[3];
  const float* qkvb = (const float*)d_in[4];
  const float* projw = (const float*)d_in[5];
  const float* projb = (const float*)d_in[6];
  const float* rph = (const float*)d_in[7];
  const float* rpw = (const float*)d_in[8];
  const float* ln2g = (const float*)d_in[9];
  const float* ln2b = (const float*)d_in[10];
  const float* w1 = (const float*)d_in[11];
  const float* b1 = (const float*)d_in[12];
  const float* w2 = (const float*)d_in[13];
  const float* b2 = (const float*)d_in[14];
  float* out = (float*)d_out;

  const size_t woff = (3840ull * 1280 + 1280ull * 1280 + 5120ull * 1280 + 1280ull * 5120) * 2;
  const int NWopts[7] = {100, 50, 25, 10, 5, 2, 1};
  int NW = 0, Mb = 0;
  for (int i = 0; i < 7; ++i) {
    int nw = NWopts[i];
    int mb = ((nw * 196 + 255) / 256) * 256;
    size_t tot = woff + (size_t)mb * 2560 /*A1*/ + (size_t)mb * 7680 /*QKV*/ +
                 (size_t)mb * 2560 /*AO*/ + (size_t)nw * 16 * 196 * 28 * 2 /*BIAS bf16*/ +
                 (size_t)mb * 2560 /*ATTN*/;
    if (tot <= ws_size) { NW = nw; Mb = mb; break; }
  }
  if (!NW) return;  // ws_size too small to run at all

  char* p = (char*)d_ws;
  unsigned short* qkvwT = (unsigned short*)p; p += 3840ull * 1280 * 2;
  unsigned short* projwT = (unsigned short*)p; p += 1280ull * 1280 * 2;
  unsigned short* w1T = (unsigned short*)p; p += 5120ull * 1280 * 2;
  unsigned short* w2T = (unsigned short*)p; p += 1280ull * 5120 * 2;
  unsigned short* A1 = (unsigned short*)p; p += (size_t)Mb * 2560;
  unsigned short* QKV = (unsigned short*)p; p += (size_t)Mb * 7680;
  unsigned short* AO = (unsigned short*)p; p += (size_t)Mb * 2560;
  unsigned short* BIAS = (unsigned short*)p; p += (size_t)NW * 16 * 196 * 28 * 2;
  unsigned short* ATTN = (unsigned short*)p;
  unsigned short* Hb = QKV;  // MLP hidden (Mb x 5120) overlays QKV+AO (contiguous, both dead)
  unsigned short* A2 = A1;   // LN2 out overlays LN1 out (dead after QKV GEMM)

  k_transpose<<<dim3(120, 40), dim3(32, 8), 0, stream>>>(qkvw, qkvwT, 1280, 3840);
  k_transpose<<<dim3(40, 40), dim3(32, 8), 0, stream>>>(projw, projwT, 1280, 1280);
  k_transpose<<<dim3(160, 40), dim3(32, 8), 0, stream>>>(w1, w1T, 1280, 5120);
  k_transpose<<<dim3(40, 160), dim3(32, 8), 0, stream>>>(w2, w2T, 5120, 1280);

  int gy = Mb / 256;
  int nchunks = (100 + NW - 1) / NW;
  for (int c = 0; c < nchunks; ++c) {
    int w0 = c * NW;
    int cw = (100 - w0 < NW) ? (100 - w0) : NW;
    int ctok = cw * 196;
    k_ln1<<<Mb / 4, 256, 0, stream>>>(x, ln1g, ln1b, A1, w0, ctok);
    k_gqkv<<<30 * gy, 512, 0, stream>>>(A1, qkvwT, 1280, 3840, 30, qkvb, (void*)QKV,
                                        nullptr, nullptr, 0, 0);
    k_relbias<<<cw * 16, 256, 0, stream>>>(QKV, rph, rpw, BIAS);
    k_attn<<<cw * 16, 512, 0, stream>>>(QKV, BIAS, AO);
    k_gproj<<<10 * gy, 512, 0, stream>>>(AO, projwT, 1280, 1280, 10, projb, (void*)ATTN,
                                         x, nullptr, w0, ctok);
    k_ln2<<<Mb / 4, 256, 0, stream>>>(ATTN, ln2g, ln2b, A2);
    k_gmlp1<<<40 * gy, 512, 0, stream>>>(A2, w1T, 1280, 5120, 40, b1, (void*)Hb,
                                         nullptr, nullptr, 0, 0);
    k_gmlp2<<<10 * gy, 512, 0, stream>>>(Hb, w2T, 5120, 1280, 10, b2, (void*)out,
                                         nullptr, ATTN, w0, ctok);
  }
}

// Round 6
// 1603.412 us; speedup vs baseline: 1.1274x; 1.1274x over previous
//
#include <hip/hip_runtime.h>

typedef __attribute__((ext_vector_type(8))) short short8;
typedef __attribute__((ext_vector_type(4))) float f32x4;

#define GLBP(p) ((const __attribute__((address_space(1))) void*)(p))
#define LDSP(p) ((__attribute__((address_space(3))) void*)(p))

__device__ __forceinline__ float bf2f(unsigned short u) {
  return __uint_as_float(((unsigned int)u) << 16);
}
__device__ __forceinline__ unsigned short f2bf(float f) {
  unsigned int u = __float_as_uint(f);
  u += 0x7fff + ((u >> 16) & 1);
  return (unsigned short)(u >> 16);
}

// global token -> (batch, pixel-y, pixel-x); windows are 14x14, 5x5 grid/batch
__device__ __forceinline__ void tok2pix(int gt, int& b, int& py, int& px) {
  int w = gt / 196, t = gt - w * 196;
  b = w / 25;
  int wr = w - b * 25;
  int wy = wr / 5, wx = wr - wy * 5;
  int ty = t / 14;
  py = wy * 14 + ty;
  px = wx * 14 + (t - ty * 14);
}

// ---------------- weight transpose fp32(K,N) -> bf16(N,K) ----------------
__global__ void k_transpose(const float* __restrict__ W, unsigned short* __restrict__ Wt,
                            int K, int N) {
  __shared__ float tile[32][33];
  int tx = threadIdx.x, ty = threadIdx.y;
  int n0 = blockIdx.x * 32, k0 = blockIdx.y * 32;
#pragma unroll
  for (int i = 0; i < 4; ++i)
    tile[ty + 8 * i][tx] = W[(size_t)(k0 + ty + 8 * i) * N + n0 + tx];
  __syncthreads();
#pragma unroll
  for (int i = 0; i < 4; ++i)
    Wt[(size_t)(n0 + ty + 8 * i) * K + k0 + tx] = f2bf(tile[tx][ty + 8 * i]);
}

// ---------------- LN1: one wave per token row ----------------
__global__ __launch_bounds__(256) void k_ln1(const float* __restrict__ x,
                                             const float* __restrict__ g,
                                             const float* __restrict__ be,
                                             unsigned short* __restrict__ A1,
                                             int w0, int ctok) {
  int m = blockIdx.x * 4 + (threadIdx.x >> 6);
  int lane = threadIdx.x & 63;
  int b, py, px;
  tok2pix(w0 * 196 + m, b, py, px);
  bool valid = (m < ctok) && (py < 64) && (px < 64);
  const float* row = x + ((size_t)((b * 64 + py) * 64 + px)) * 1280;
  float v[20];
#pragma unroll
  for (int i = 0; i < 20; ++i) v[i] = valid ? row[lane + 64 * i] : 0.f;
  float s = 0.f, ss = 0.f;
#pragma unroll
  for (int i = 0; i < 20; ++i) { s += v[i]; ss += v[i] * v[i]; }
#pragma unroll
  for (int o = 32; o > 0; o >>= 1) { s += __shfl_down(s, o); ss += __shfl_down(ss, o); }
  s = __shfl(s, 0);
  ss = __shfl(ss, 0);
  float mu = s * (1.f / 1280.f);
  float var = ss * (1.f / 1280.f) - mu * mu;
  float rinv = rsqrtf(var + 1e-6f);
  unsigned short* o1 = A1 + (size_t)m * 1280;
#pragma unroll
  for (int i = 0; i < 20; ++i) {
    int c = lane + 64 * i;
    o1[c] = f2bf((v[i] - mu) * rinv * g[c] + be[c]);
  }
}

// ---------------- LN2: one wave per bf16 row ----------------
__global__ __launch_bounds__(256) void k_ln2(const unsigned short* __restrict__ AT,
                                             const float* __restrict__ g,
                                             const float* __restrict__ be,
                                             unsigned short* __restrict__ A2) {
  int m = blockIdx.x * 4 + (threadIdx.x >> 6);
  int lane = threadIdx.x & 63;
  const unsigned short* row = AT + (size_t)m * 1280;
  float v[20];
#pragma unroll
  for (int i = 0; i < 20; ++i) v[i] = bf2f(row[lane + 64 * i]);
  float s = 0.f, ss = 0.f;
#pragma unroll
  for (int i = 0; i < 20; ++i) { s += v[i]; ss += v[i] * v[i]; }
#pragma unroll
  for (int o = 32; o > 0; o >>= 1) { s += __shfl_down(s, o); ss += __shfl_down(ss, o); }
  s = __shfl(s, 0);
  ss = __shfl(ss, 0);
  float mu = s * (1.f / 1280.f);
  float var = ss * (1.f / 1280.f) - mu * mu;
  float rinv = rsqrtf(var + 1e-6f);
  unsigned short* o1 = A2 + (size_t)m * 1280;
#pragma unroll
  for (int i = 0; i < 20; ++i) {
    int c = lane + 64 * i;
    o1[c] = f2bf((v[i] - mu) * rinv * g[c] + be[c]);
  }
}

// ---------------- 256x128 bf16 GEMM, BK=32, 3-slot ring (72KB -> 2 blocks/CU) ----------------
// C[M,N] = A[M,K] * Bt[N,K]^T ; one barrier + one counted vmcnt per K-tile.
// LDS swizzle: 16B-chunk index ^= (row>>1)&3 (2-way max on ds_read_b128; source pre-swizzled).
// EPI 0: +bias -> head-major QKV bf16 [w][nh][qkv][196][80]
//     1: +bias+win-residual -> bf16 ATTN   2: +bias+gelu -> bf16 (MLP1)
//     3: +bias+attnres -> f32 out, window->image crop (MLP2)
template <int EPI>
__device__ __forceinline__ void gemm_body(const unsigned short* __restrict__ A,
                                          const unsigned short* __restrict__ Bt,
                                          int K, int N, int gx,
                                          const float* __restrict__ bias,
                                          void* __restrict__ outp,
                                          const float* __restrict__ xres,
                                          const unsigned short* __restrict__ attnres,
                                          int w0, int ctok) {
  __shared__ __align__(16) char smem[73728];  // 3 slots x (A 16KB + B 8KB)
  int tid = threadIdx.x;
  int w = tid >> 6, lane = tid & 63;
  // bijective XCD swizzle (m204)
  int nwg = gridDim.x, bid = blockIdx.x;
  int q = nwg >> 3, r = nwg & 7;
  int xcd = bid & 7, loc = bid >> 3;
  int wg = (xcd < r ? xcd * (q + 1) : r * (q + 1) + (xcd - r) * q) + loc;
  int bx = wg % gx, by = wg / gx;
  int mBase = by * 256, nBase = bx * 128;
  int wr = w >> 2, wc = w & 3;
  int la = lane & 15, lg = lane >> 4;

  // staging: thread covers LDS byte tid*16 of each 8KB sub-region; row=tid>>2, chunk=tid&3
  int srow = tid >> 2;
  int schunk = (tid & 3) ^ ((srow >> 1) & 3);  // pre-swizzled source chunk
  const char* pa0 = (const char*)A + (size_t)(mBase + srow) * K * 2 + (schunk << 4);
  const char* pa1 = (const char*)A + (size_t)(mBase + 128 + srow) * K * 2 + (schunk << 4);
  const char* pb0 = (const char*)Bt + (size_t)(nBase + srow) * K * 2 + (schunk << 4);
  int ldst = tid * 16;

  auto STAGE = [&](int slot, size_t ko) {
    int b = slot * 24576;
    __builtin_amdgcn_global_load_lds(GLBP(pa0 + ko), LDSP(smem + b + ldst), 16, 0, 0);
    __builtin_amdgcn_global_load_lds(GLBP(pa1 + ko), LDSP(smem + b + 8192 + ldst), 16, 0, 0);
    __builtin_amdgcn_global_load_lds(GLBP(pb0 + ko), LDSP(smem + b + 16384 + ldst), 16, 0, 0);
  };

  // fragment read offsets (per-thread constants), same XOR swizzle on read side
  int offA[8], offB[2];
#pragma unroll
  for (int m = 0; m < 8; ++m) {
    int rr = wr * 128 + m * 16 + la;
    offA[m] = rr * 64 + ((lg ^ ((rr >> 1) & 3)) << 4);
  }
#pragma unroll
  for (int n = 0; n < 2; ++n) {
    int rr = wc * 32 + n * 16 + la;
    offB[n] = 16384 + rr * 64 + ((lg ^ ((rr >> 1) & 3)) << 4);
  }

  const f32x4 z4 = {0.f, 0.f, 0.f, 0.f};
  f32x4 acc[8][2];
#pragma unroll
  for (int m = 0; m < 8; ++m)
#pragma unroll
    for (int n = 0; n < 2; ++n) acc[m][n] = z4;

  int NT = K >> 5;
  STAGE(0, 0);
  STAGE(1, 64);
  int rs = 0;
  for (int t = 0; t < NT; ++t) {
    if (t + 1 < NT)
      asm volatile("s_waitcnt vmcnt(3)" ::: "memory");
    else
      asm volatile("s_waitcnt vmcnt(0)" ::: "memory");
    __builtin_amdgcn_s_barrier();
    __builtin_amdgcn_sched_barrier(0);
    if (t + 2 < NT) {
      int ws = rs + 2;
      if (ws >= 3) ws -= 3;
      STAGE(ws, (size_t)(t + 2) * 64);
    }
    const char* buf = (const char*)smem + rs * 24576;
    short8 af[4], bfr[2];
#pragma unroll
    for (int n = 0; n < 2; ++n) bfr[n] = *(const short8*)(buf + offB[n]);
#pragma unroll
    for (int m = 0; m < 4; ++m) af[m] = *(const short8*)(buf + offA[m]);
    __builtin_amdgcn_s_setprio(1);
#pragma unroll
    for (int m = 0; m < 4; ++m)
#pragma unroll
      for (int n = 0; n < 2; ++n)
        acc[m][n] = __builtin_amdgcn_mfma_f32_16x16x32_bf16(af[m], bfr[n], acc[m][n], 0, 0, 0);
    __builtin_amdgcn_s_setprio(0);
    __builtin_amdgcn_sched_barrier(0);
#pragma unroll
    for (int m = 0; m < 4; ++m) af[m] = *(const short8*)(buf + offA[m + 4]);
    __builtin_amdgcn_s_setprio(1);
#pragma unroll
    for (int m = 0; m < 4; ++m)
#pragma unroll
      for (int n = 0; n < 2; ++n)
        acc[m + 4][n] = __builtin_amdgcn_mfma_f32_16x16x32_bf16(af[m], bfr[n], acc[m + 4][n], 0, 0, 0);
    __builtin_amdgcn_s_setprio(0);
    rs = (rs == 2) ? 0 : rs + 1;
  }

#pragma unroll
  for (int m = 0; m < 8; ++m) {
#pragma unroll
    for (int n = 0; n < 2; ++n) {
      int col = nBase + wc * 32 + n * 16 + la;
      float bcol = bias[col];
#pragma unroll
      for (int j = 0; j < 4; ++j) {
        int row = mBase + wr * 128 + m * 16 + lg * 4 + j;
        float v = acc[m][n][j] + bcol;
        if (EPI == 0) {
          if (row < ctok) {
            int wloc = row / 196, tt = row - wloc * 196;
            int which = col / 1280, cr = col - which * 1280;
            int nh = cr / 80, d = cr - nh * 80;
            ((unsigned short*)outp)[((((size_t)wloc * 16 + nh) * 3 + which) * 196 + tt) * 80 + d] =
                f2bf(v);
          }
        } else if (EPI == 2) {
          float gg = 0.5f * v * (1.f + erff(v * 0.70710678118654752f));
          ((unsigned short*)outp)[(size_t)row * N + col] = f2bf(gg);
        } else if (EPI == 1) {
          if (row < ctok) {
            int b, py, px;
            tok2pix(w0 * 196 + row, b, py, px);
            float wv = (py < 64 && px < 64)
                           ? xres[((size_t)((b * 64 + py) * 64 + px)) * 1280 + col]
                           : 0.f;
            ((unsigned short*)outp)[(size_t)row * 1280 + col] = f2bf(v + wv);
          }
        } else {
          if (row < ctok) {
            int b, py, px;
            tok2pix(w0 * 196 + row, b, py, px);
            if (py < 64 && px < 64)
              ((float*)outp)[((size_t)((b * 64 + py) * 64 + px)) * 1280 + col] =
                  v + bf2f(attnres[(size_t)row * 1280 + col]);
          }
        }
      }
    }
  }
}

__global__ __launch_bounds__(512, 4) void k_gqkv(const unsigned short* A, const unsigned short* Bt,
                                                 int K, int N, int gx, const float* bias, void* o,
                                                 const float* xr, const unsigned short* ar, int w0, int ct) {
  gemm_body<0>(A, Bt, K, N, gx, bias, o, xr, ar, w0, ct);
}
__global__ __launch_bounds__(512, 4) void k_gproj(const unsigned short* A, const unsigned short* Bt,
                                                  int K, int N, int gx, const float* bias, void* o,
                                                  const float* xr, const unsigned short* ar, int w0, int ct) {
  gemm_body<1>(A, Bt, K, N, gx, bias, o, xr, ar, w0, ct);
}
__global__ __launch_bounds__(512, 4) void k_gmlp1(const unsigned short* A, const unsigned short* Bt,
                                                  int K, int N, int gx, const float* bias, void* o,
                                                  const float* xr, const unsigned short* ar, int w0, int ct) {
  gemm_body<2>(A, Bt, K, N, gx, bias, o, xr, ar, w0, ct);
}
__global__ __launch_bounds__(512, 4) void k_gmlp2(const unsigned short* A, const unsigned short* Bt,
                                                  int K, int N, int gx, const float* bias, void* o,
                                                  const float* xr, const unsigned short* ar, int w0, int ct) {
  gemm_body<3>(A, Bt, K, N, gx, bias, o, xr, ar, w0, ct);
}

// ---------------- attention: fused rel-bias, head-major QKV, XCD-grouped blocks ----------------
// bid = r + 8*nh + 128*a ; window w = 8a + r -> all 16 heads of a window share an XCD (bid%8==w%8)
__global__ __launch_bounds__(512) void k_attn(const unsigned short* __restrict__ qkv,
                                              const float* __restrict__ rph,
                                              const float* __restrict__ rpw,
                                              unsigned short* __restrict__ AO, int cw) {
  int bid = blockIdx.x;
  int r = bid & 7, nh = (bid >> 3) & 15, a = bid >> 7;
  int w = 8 * a + r;
  if (w >= cw) return;

  __shared__ unsigned short Ks[208 * 104];  // [key][d] (stride 52dw: 2-way free)
  __shared__ unsigned short Vt[80 * 248];   // [d][key] (stride 124dw: 2-way free)
  __shared__ unsigned short Ps[8][16 * 248];
  __shared__ unsigned short Bls[196 * 28];  // bf16 bias: [t][0..13]=bh(ky), [14..27]=bw(kx)
  int tid = threadIdx.x, wid = tid >> 6, lane = tid & 63;
  int la = lane & 15, lg = lane >> 4;
  const unsigned short* qb = qkv + ((size_t)(w * 16 + nh)) * 3 * 15680;
  const unsigned short* kb = qb + 15680;
  const unsigned short* vb = qb + 31360;
  const short8 z8 = {0, 0, 0, 0, 0, 0, 0, 0};

  // K -> LDS (coalesced contiguous rows of 160B)
  for (int c = tid; c < 208 * 13; c += 512) {
    int t = c / 13, seg = c - t * 13;
    short8 kv = z8;
    if (t < 196 && seg < 10) kv = *(const short8*)(kb + (size_t)t * 80 + seg * 8);
    *(short8*)(Ks + t * 104 + seg * 8) = kv;
  }
  // V -> LDS transposed
  for (int c = tid; c < 196 * 10; c += 512) {
    int t = c / 10, d8 = (c - t * 10) * 8;
    short8 vv = *(const short8*)(vb + (size_t)t * 80 + d8);
#pragma unroll
    for (int e = 0; e < 8; ++e) Vt[(d8 + e) * 248 + t] = (unsigned short)vv[e];
  }
  for (int i = tid; i < 80 * 52; i += 512) Vt[(i / 52) * 248 + 196 + (i % 52)] = 0;
  // fused decomposed rel-pos bias (q rows are L2/L1-hot, contiguous)
  for (int id = tid; id < 196 * 28; id += 512) {
    int t = id / 28, c = id - t * 28;
    int y = t / 14, xx = t - y * 14;
    const float* R = (c < 14) ? (rph + (size_t)(y - c + 13) * 80)
                              : (rpw + (size_t)(xx - (c - 14) + 13) * 80);
    const unsigned short* qq = qb + (size_t)t * 80;
    float acc = 0.f;
#pragma unroll
    for (int d8 = 0; d8 < 10; ++d8) {
      short8 qv = *(const short8*)(qq + d8 * 8);
      const float4* Rv = (const float4*)(R + d8 * 8);
      float4 ra = Rv[0], rb = Rv[1];
      acc += bf2f((unsigned short)qv[0]) * ra.x + bf2f((unsigned short)qv[1]) * ra.y +
             bf2f((unsigned short)qv[2]) * ra.z + bf2f((unsigned short)qv[3]) * ra.w +
             bf2f((unsigned short)qv[4]) * rb.x + bf2f((unsigned short)qv[5]) * rb.y +
             bf2f((unsigned short)qv[6]) * rb.z + bf2f((unsigned short)qv[7]) * rb.w;
    }
    Bls[id] = f2bf(acc);
  }
  __syncthreads();

  int kyv[13], kxv[13];
#pragma unroll
  for (int ci = 0; ci < 13; ++ci) {
    int key = ci * 16 + la;
    kyv[ci] = key / 14;
    kxv[ci] = key - kyv[ci] * 14;
  }

  const float scale = 0.111803398874989485f;  // 80^-0.5
  const f32x4 z4 = {0.f, 0.f, 0.f, 0.f};
  unsigned short* P = Ps[wid];

  auto process = [&](int rb) {
    short8 qa[3];
#pragma unroll
    for (int kk = 0; kk < 3; ++kk) {
      int t = rb * 16 + la;
      int d = kk * 32 + lg * 8;
      qa[kk] = (t < 196 && d < 80) ? *(const short8*)(qb + (size_t)t * 80 + d) : z8;
    }
    f32x4 s[13];
#pragma unroll
    for (int i = 0; i < 13; ++i) s[i] = z4;
#pragma unroll
    for (int kk = 0; kk < 3; ++kk) {
#pragma unroll
      for (int ni = 0; ni < 13; ++ni) {
        short8 bb = *(const short8*)(Ks + (ni * 16 + la) * 104 + kk * 32 + lg * 8);
        s[ni] = __builtin_amdgcn_mfma_f32_16x16x32_bf16(qa[kk], bb, s[ni], 0, 0, 0);
      }
    }
#pragma unroll
    for (int j = 0; j < 4; ++j) {
      int rloc = lg * 4 + j;
      int t = rb * 16 + rloc;
      bool tval = t < 196;
      const unsigned short* Bp = Bls + (tval ? t : 0) * 28;
      float v[13];
      float mx = -3e30f;
#pragma unroll
      for (int ci = 0; ci < 13; ++ci) {
        int key = ci * 16 + la;
        float val = s[ci][j] * scale;
        if (key < 196 && tval) val += bf2f(Bp[kyv[ci]]) + bf2f(Bp[14 + kxv[ci]]);
        if (key >= 196) val = -3e30f;
        v[ci] = val;
        mx = fmaxf(mx, val);
      }
#pragma unroll
      for (int o = 1; o < 16; o <<= 1) mx = fmaxf(mx, __shfl_xor(mx, o));
      float sum = 0.f;
#pragma unroll
      for (int ci = 0; ci < 13; ++ci) {
        float e = __expf(v[ci] - mx);
        v[ci] = e;
        sum += e;
      }
#pragma unroll
      for (int o = 1; o < 16; o <<= 1) sum += __shfl_xor(sum, o);
      float inv = 1.f / sum;
#pragma unroll
      for (int ci = 0; ci < 13; ++ci) P[rloc * 248 + ci * 16 + la] = f2bf(v[ci] * inv);
      P[rloc * 248 + 208 + la] = 0;
    }
    f32x4 o5[5];
#pragma unroll
    for (int i = 0; i < 5; ++i) o5[i] = z4;
#pragma unroll
    for (int kc = 0; kc < 7; ++kc) {
      short8 aa = *(const short8*)(P + la * 248 + kc * 32 + lg * 8);
#pragma unroll
      for (int ni = 0; ni < 5; ++ni) {
        short8 bb = *(const short8*)(Vt + (ni * 16 + la) * 248 + kc * 32 + lg * 8);
        o5[ni] = __builtin_amdgcn_mfma_f32_16x16x32_bf16(aa, bb, o5[ni], 0, 0, 0);
      }
    }
#pragma unroll
    for (int ni = 0; ni < 5; ++ni)
#pragma unroll
      for (int j = 0; j < 4; ++j) {
        int t = rb * 16 + lg * 4 + j;
        if (t < 196)
          AO[((size_t)w * 196 + t) * 1280 + nh * 80 + ni * 16 + la] = f2bf(o5[ni][j]);
      }
  };

  process(wid);                   // rb 0..7
  if (wid < 5) process(wid + 8);  // rb 8..12
}

extern "C" void kernel_launch(void* const* d_in, const int* in_sizes, int n_in,
                              void* d_out, int out_size, void* d_ws, size_t ws_size,
                              hipStream_t stream) {
  const float* x = (const float*)d_in[0];
  const float* ln1g = (const float*)d_in[1];
  const float* ln1b = (const float*)d_in[2];
  const float* qkvw = (const float*)d_in[3];
  const float* qkvb = (const float*)d_in[4];
  const float* projw = (const float*)d_in[5];
  const float* projb = (const float*)d_in[6];
  const float* rph = (const float*)d_in[7];
  const float* rpw = (const float*)d_in[8];
  const float* ln2g = (const float*)d_in[9];
  const float* ln2b = (const float*)d_in[10];
  const float* w1 = (const float*)d_in[11];
  const float* b1 = (const float*)d_in[12];
  const float* w2 = (const float*)d_in[13];
  const float* b2 = (const float*)d_in[14];
  float* out = (float*)d_out;

  const size_t woff = (3840ull * 1280 + 1280ull * 1280 + 5120ull * 1280 + 1280ull * 5120) * 2;
  const int NWopts[7] = {100, 50, 25, 10, 5, 2, 1};
  int NW = 0, Mb = 0;
  for (int i = 0; i < 7; ++i) {
    int nw = NWopts[i];
    int mb = ((nw * 196 + 255) / 256) * 256;
    size_t tot = woff + (size_t)mb * 2560 /*A1*/ + (size_t)mb * 7680 /*QKV*/ +
                 (size_t)mb * 2560 /*AO*/ + (size_t)mb * 2560 /*ATTN*/;
    if (tot <= ws_size) { NW = nw; Mb = mb; break; }
  }
  if (!NW) return;  // ws_size too small to run at all

  char* p = (char*)d_ws;
  unsigned short* qkvwT = (unsigned short*)p; p += 3840ull * 1280 * 2;
  unsigned short* projwT = (unsigned short*)p; p += 1280ull * 1280 * 2;
  unsigned short* w1T = (unsigned short*)p; p += 5120ull * 1280 * 2;
  unsigned short* w2T = (unsigned short*)p; p += 1280ull * 5120 * 2;
  unsigned short* A1 = (unsigned short*)p; p += (size_t)Mb * 2560;
  unsigned short* QKV = (unsigned short*)p; p += (size_t)Mb * 7680;  // head-major usage fits
  unsigned short* AO = (unsigned short*)p; p += (size_t)Mb * 2560;
  unsigned short* ATTN = (unsigned short*)p;
  unsigned short* Hb = QKV;  // MLP hidden (Mb x 5120) overlays QKV+AO (contiguous, both dead)
  unsigned short* A2 = A1;   // LN2 out overlays LN1 out (dead after QKV GEMM)

  k_transpose<<<dim3(120, 40), dim3(32, 8), 0, stream>>>(qkvw, qkvwT, 1280, 3840);
  k_transpose<<<dim3(40, 40), dim3(32, 8), 0, stream>>>(projw, projwT, 1280, 1280);
  k_transpose<<<dim3(160, 40), dim3(32, 8), 0, stream>>>(w1, w1T, 1280, 5120);
  k_transpose<<<dim3(40, 160), dim3(32, 8), 0, stream>>>(w2, w2T, 5120, 1280);

  int gy = Mb / 256;
  int nchunks = (100 + NW - 1) / NW;
  for (int c = 0; c < nchunks; ++c) {
    int w0 = c * NW;
    int cw = (100 - w0 < NW) ? (100 - w0) : NW;
    int ctok = cw * 196;
    k_ln1<<<Mb / 4, 256, 0, stream>>>(x, ln1g, ln1b, A1, w0, ctok);
    k_gqkv<<<30 * gy, 512, 0, stream>>>(A1, qkvwT, 1280, 3840, 30, qkvb, (void*)QKV,
                                        nullptr, nullptr, 0, ctok);
    int ablk = ((cw + 7) / 8) * 128;
    k_attn<<<ablk, 512, 0, stream>>>(QKV, rph, rpw, AO, cw);
    k_gproj<<<10 * gy, 512, 0, stream>>>(AO, projwT, 1280, 1280, 10, projb, (void*)ATTN,
                                         x, nullptr, w0, ctok);
    k_ln2<<<Mb / 4, 256, 0, stream>>>(ATTN, ln2g, ln2b, A2);
    k_gmlp1<<<40 * gy, 512, 0, stream>>>(A2, w1T, 1280, 5120, 40, b1, (void*)Hb,
                                         nullptr, nullptr, 0, ctok);
    k_gmlp2<<<10 * gy, 512, 0, stream>>>(Hb, w2T, 5120, 1280, 10, b2, (void*)out,
                                         nullptr, ATTN, w0, ctok);
  }
}